// Round 10
// baseline (143.793 us; speedup 1.0000x reference)
//
#include <hip/hip_runtime.h>
#include <hip/hip_bf16.h>
#include <hip/hip_fp16.h>

// TopologicalDecoder via MFMA. B=262144, L=16, H=64, C=8, O=32. f32 in/out.
// R9 (resubmit; prior run died to container-acquire infra flake, no data) =
// R5 (champion: 44us, no spill) + 1-deep software pipeline:
//   - scratch double-buffered (scrA=g1, scrB=g2; LDS 32768->40960 = 4x/CU
//     at exactly the 160KiB pool)
//   - ADVANCE(t+1) = {rc fetch, GEMM1, LN, g1->scrA} hoisted between
//     GEMM2(t)'s g2->scrB writes and the drain => ONE lgkmcnt(0) drain per
//     iteration (was two), each preceded by ~20 MFMA of issued work.
//   - A2(t+1) read directly after the drain, hidden under GEMM3(t)+store.
// R8 lesson applied: nothing memory-sourced between drain and use; z/ztx
// prefetch stays as raw float4 regs consumed a full stage later.
//
// GEMM1: U[b,160] @ Waug[160,64] (biases folded, kt-outer). GEMM2 unswapped
// + b1 + gelu -> scrB. GEMM3 + b2, coalesced store.
// MFMA 16x16x32 bf16. A: m=lane&15,k=q*8+j; B: n=lane&15,same k;
// C/D: col=lane&15,row=q*4+reg (verified).

typedef __attribute__((ext_vector_type(8))) short short8;
typedef __attribute__((ext_vector_type(4))) float f32x4;

__device__ __forceinline__ int pkbf2(float a, float b) {
    union { __hip_bfloat162 h2; int i; } u;
    u.h2 = __float22bfloat162_rn(make_float2(a, b));   // v_cvt_pk_bf16_f32
    return u.i;
}
__device__ __forceinline__ short pkbf1(float a) { return (short)pkbf2(a, 0.f); }

// fast GELU (tanh-form): max abs err ~4e-4
__device__ __forceinline__ float gelu_fast(float x) {
    float x2 = x * x;
    float t  = __expf(fmaf(x2, 0.07135481f, 1.5957691f) * x);
    float r  = __builtin_amdgcn_rcpf(t + 1.0f);
    return fmaf(-x, r, x);
}
// packed-fragment flat short index for B[k][n] matrices (KT = K/32 tiles)
__device__ __forceinline__ int bpack(int k, int n, int KT) {
    return (((n >> 4) * KT + (k >> 5)) * 64 + (n & 15) + (((k & 31) >> 3) << 4)) * 8 + (k & 7);
}
// scratch group swizzle: spreads scatter writes across banks (0 conflicts measured)
__device__ __forceinline__ int gswz(int g) {
    return g ^ (((g >> 4) & 3) << 1) ^ ((g >> 3) & 1);
}
// pack 8 consecutive f32 into a bf16 fragment row
__device__ __forceinline__ short8 packrow8(const float* base) {
    const float4* p = (const float4*)base;
    float4 a = p[0], b = p[1];
    union { short8 s; int i[4]; } f;
    f.i[0] = pkbf2(a.x, a.y); f.i[1] = pkbf2(a.z, a.w);
    f.i[2] = pkbf2(b.x, b.y); f.i[3] = pkbf2(b.z, b.w);
    return f.s;
}

// ws layout (shorts): [0,10240) WAug bpack | [10240,14336) W1 frags | [14336,16384) W2 frags
// (bytes) [32768,32896) cvals float4[8] = {csq, 1-csq, 0.1*rb, 0}
// Parallel pack: blocks 0..39 -> WAug (1 elem/thread), 40 -> W1, 41 -> W2, 42 -> cvals.
__global__ void pack_weights(const float* __restrict__ cw, const float* __restrict__ cb,
                             const float* __restrict__ txw, const float* __restrict__ txb,
                             const float* __restrict__ w1,  const float* __restrict__ w2,
                             const float* __restrict__ cen, const float* __restrict__ rb,
                             short* __restrict__ ws)
{
    const int tid = threadIdx.x;
    const int b = blockIdx.x;
    if (b < 40) {
        int idx = b * 256 + tid;               // [0,10240)
        int k = idx >> 6, n = idx & 63;
        float v;
        if (k < 128)       v = cw[(k >> 4) * 1024 + n * 16 + (k & 15)];
        else if (k < 144)  v = txw[n * 16 + (k - 128)];
        else if (k < 152)  v = cb[(k - 144) * 64 + n];
        else if (k == 152) v = txb[n];
        else               v = 0.f;
        ws[bpack(k, n, 5)] = pkbf1(v);
    } else if (b == 40) {
        for (int f = tid; f < 512; f += 256) {          // W1: (nt,kt,lane)
            int lane = f & 63, e = f >> 6;
            int nt = e >> 1, kt = e & 1;
            int col = lane & 15, qq = lane >> 4;
            *(short8*)(ws + 10240 + f * 8) =
                packrow8(w1 + (nt * 16 + col) * 64 + kt * 32 + qq * 8);
        }
    } else if (b == 41) {
        int f = tid;                                     // W2: 256 entries
        int lane = f & 63, e = f >> 6;
        int nt = e >> 1, kt = e & 1;
        int col = lane & 15, qq = lane >> 4;
        *(short8*)(ws + 14336 + f * 8) =
            packrow8(w2 + (nt * 16 + col) * 64 + kt * 32 + qq * 8);
    } else {
        if (tid < 8) {
            float csq = 0.f;
            for (int l = 0; l < 16; l++) { float cv = cen[tid * 16 + l]; csq = fmaf(cv, cv, csq); }
            ((float4*)((char*)ws + 32768))[tid] =
                make_float4(csq, 1.0f - csq, 0.1f * rb[tid], 0.f);
        }
    }
}

// LDS (bytes): WAug 20480 | scrA 4x2048 | scrB 4x2048 | W2L 4096 = 40960 (= 160KiB/4)
constexpr int SCRA_OFF = 20480;
constexpr int SCRB_OFF = 28672;
constexpr int W2L_OFF  = 36864;
constexpr int SMEM_SZ  = 40960;

__global__ __launch_bounds__(256, 4) void topo_mfma(
    const float* __restrict__ zg,  const float* __restrict__ ztx,
    const float* __restrict__ cw,  const float* __restrict__ cb,
    const float* __restrict__ rw,  const float* __restrict__ rb,
    const float* __restrict__ cen, const float* __restrict__ txw,
    const float* __restrict__ txb, const float* __restrict__ lng,
    const float* __restrict__ lnb, const float* __restrict__ w1,
    const float* __restrict__ b1,  const float* __restrict__ w2,
    const float* __restrict__ b2,  const short* __restrict__ wsp,
    const int prepacked,
    float* __restrict__ out, int Btot)
{
    __shared__ __align__(16) char smem[SMEM_SZ];
    short* WA = (short*)smem;
    const short8* W2L = (const short8*)(smem + W2L_OFF);

    const int tid = threadIdx.x;
    const int wv = tid >> 6, lane = tid & 63;
    const int q = lane >> 4, col = lane & 15;
    const int sub = (lane >> 3) & 1, j = lane & 7;

    // ---- stage WAug + W2 fragments into LDS ----
    if (prepacked) {
        const int4* src = (const int4*)wsp;
        int4* dst = (int4*)smem;
        #pragma unroll
        for (int i = 0; i < 5; i++) dst[i * 256 + tid] = src[i * 256 + tid];
        ((int4*)(smem + W2L_OFF))[tid] = ((const int4*)((const char*)wsp + 28672))[tid];
    } else {
        for (int idx = tid; idx < 160 * 64; idx += 256) {
            int k = idx >> 6, n = idx & 63;
            float v;
            if (k < 128)       v = cw[(k >> 4) * 1024 + n * 16 + (k & 15)];
            else if (k < 144)  v = txw[n * 16 + (k - 128)];
            else if (k < 152)  v = cb[(k - 144) * 64 + n];
            else if (k == 152) v = txb[n];
            else               v = 0.f;
            WA[bpack(k, n, 5)] = pkbf1(v);
        }
        {   // W2 frags -> LDS (256 entries, one per thread)
            int e = tid >> 6, ln = tid & 63;
            int nt = e >> 1, kt = e & 1;
            *(short8*)(smem + W2L_OFF + (e * 64 + ln) * 16) =
                packrow8(w2 + (nt * 16 + (ln & 15)) * 64 + kt * 32 + (ln >> 4) * 8);
        }
    }

    // ---- router (f32, own sample; branchless fast acosh, cvals-prepacked) ----
    // Result kept in registers: rsh = {charts(0,2),(4,6),(1,3),(5,7)} as f16 pairs.
    const long sG = (long)blockIdx.x * 256 + tid;
    int4 rsh;
    {
        float z[16];
        const float4* pg = (const float4*)(zg + sG * 16);
        #pragma unroll
        for (int v = 0; v < 4; v++) {
            float4 a = pg[v];
            z[v*4+0]=a.x; z[v*4+1]=a.y; z[v*4+2]=a.z; z[v*4+3]=a.w;
        }
        float r2 = 0.f;
        #pragma unroll
        for (int l = 0; l < 16; l++) r2 = fmaf(z[l], z[l], r2);
        const float inv_tau = __builtin_amdgcn_rcpf(fmaxf(2.0f * fmaxf(1.0f - r2, 0.001f), 0.01f));
        const float omr2 = 1.0f - r2;
        const float4* cvp = (const float4*)((const char*)wsp + 32768);
        float scv[8]; float smax = -1e30f;
        #pragma unroll
        for (int c = 0; c < 8; c++) {
            float csq, omc2, rb1;
            if (prepacked) {
                float4 kv = cvp[c]; csq = kv.x; omc2 = kv.y; rb1 = kv.z;
            } else {
                csq = 0.f;
                #pragma unroll
                for (int l = 0; l < 16; l++) { float cv = cen[c*16+l]; csq = fmaf(cv, cv, csq); }
                omc2 = 1.0f - csq; rb1 = 0.1f * rb[c];
            }
            const float4* cp = (const float4*)(cen + c * 16);
            const float4* rp = (const float4*)(rw  + c * 16);
            float zc = 0.f, dotv = 0.f;
            #pragma unroll
            for (int v = 0; v < 4; v++) {
                float4 cv = cp[v], rv = rp[v];
                zc   = fmaf(z[v*4+0],cv.x, fmaf(z[v*4+1],cv.y,
                       fmaf(z[v*4+2],cv.z, fmaf(z[v*4+3],cv.w, zc))));
                dotv = fmaf(z[v*4+0],rv.x, fmaf(z[v*4+1],rv.y,
                       fmaf(z[v*4+2],rv.z, fmaf(z[v*4+3],rv.w, dotv))));
            }
            float dsq = fmaf(-2.0f, zc, r2 + csq);
            float u = 2.0f * dsq * __builtin_amdgcn_rcpf(omr2 * omc2 + 0.001f);
            u = fmaxf(u, 0.001f);
            float dist  = __logf((1.0f + u) + __builtin_amdgcn_sqrtf(u * (u + 2.0f)));
            float score = (fmaf(0.1f, dotv, rb1) - dist) * inv_tau;
            scv[c] = score; smax = fmaxf(smax, score);
        }
        float esum = 0.f;
        #pragma unroll
        for (int c = 0; c < 8; c++) { scv[c] = __expf(scv[c] - smax); esum += scv[c]; }
        const float rinv = __builtin_amdgcn_rcpf(esum);
        union { ushort us[8]; int4 v; } hv;
        #pragma unroll
        for (int c = 0; c < 8; c++) {
            scv[c] *= rinv;
            hv.us[(c & 1) * 4 + (c >> 1)] = __half_as_ushort(__float2half_rn(scv[c]));
        }
        rsh = hv.v;
        float4* pr = (float4*)(out + (long)Btot * 32 + sG * 8);
        pr[0] = make_float4(scv[0], scv[1], scv[2], scv[3]);
        pr[1] = make_float4(scv[4], scv[5], scv[6], scv[7]);
    }

    // ---- per-wave register B-fragments for w1^T ----
    short8 W1F[4][2];
    if (prepacked) {
        const short8* p1 = (const short8*)(wsp + 10240);
        #pragma unroll
        for (int nt = 0; nt < 4; nt++)
            #pragma unroll
            for (int kt = 0; kt < 2; kt++)
                W1F[nt][kt] = p1[(nt * 2 + kt) * 64 + lane];
    } else {
        const int kb = q * 8;
        #pragma unroll
        for (int nt = 0; nt < 4; nt++)
            #pragma unroll
            for (int kt = 0; kt < 2; kt++)
                W1F[nt][kt] = packrow8(w1 + (nt * 16 + col) * 64 + kt * 32 + kb);
    }
    // ---- per-lane epilogue constants (col-indexed, 14 regs) ----
    float lngv[4], lnbv[4], b1v[4], b2v[2];
    #pragma unroll
    for (int nt = 0; nt < 4; nt++) {
        lngv[nt] = lng[nt * 16 + col];
        lnbv[nt] = lnb[nt * 16 + col];
        b1v[nt]  = b1[nt * 16 + col];
    }
    b2v[0] = b2[col]; b2v[1] = b2[16 + col];

    __syncthreads();

    short* scrA = (short*)(smem + SCRA_OFF) + wv * 1024;
    short* scrB = (short*)(smem + SCRB_OFF) + wv * 1024;
    union Frag { short8 s; int i[4]; };

    const long blockBase = (long)blockIdx.x * 256;
    const float* zrow = zg  + (blockBase + wv * 64 + col) * 16 + ((q & 1) << 3);
    const float* trow = ztx + (blockBase + wv * 64 + col) * 16 + ((q & 1) << 3);

    float4 za = ((const float4*)zrow)[0], zb = ((const float4*)zrow)[1];
    float4 ta = ((const float4*)trow)[0], tb = ((const float4*)trow)[1];

    // ADVANCE(tn): rc fetch, GEMM1(tn), prefetch z(tn+1), one-pass LN,
    // g1 = gelu(LN) -> scrA. Consumes za/zb/ta/tb (= z(tn)); reloads them.
    auto ADVANCE = [&](int tn) {
        const int srcLn = tn * 16 + col;     // intra-wave owner lane of sample
        int4 got;
        got.x = __shfl(rsh.x, srcLn);
        got.y = __shfl(rsh.y, srcLn);
        got.z = __shfl(rsh.z, srcLn);
        got.w = __shfl(rsh.w, srcLn);
        float rc[4];
        {
            int w0 = (q < 2) ? got.x : got.z;   // charts (0,2) or (1,3)
            int w1s = (q < 2) ? got.y : got.w;  // charts (4,6) or (5,7)
            float2 f0 = __half22float2(*(__half2*)&w0);
            float2 f1 = __half22float2(*(__half2*)&w1s);
            rc[0] = f0.x; rc[1] = f0.y; rc[2] = f1.x; rc[3] = f1.y;
        }

        f32x4 acc[4] = {{0.f,0.f,0.f,0.f},{0.f,0.f,0.f,0.f},{0.f,0.f,0.f,0.f},{0.f,0.f,0.f,0.f}};
        #pragma unroll
        for (int kt = 0; kt < 4; kt++) {
            float r = rc[kt];
            Frag f;
            f.i[0] = pkbf2(r * za.x, r * za.y);
            f.i[1] = pkbf2(r * za.z, r * za.w);
            f.i[2] = pkbf2(r * zb.x, r * zb.y);
            f.i[3] = pkbf2(r * zb.z, r * zb.w);
            #pragma unroll
            for (int nt = 0; nt < 4; nt++) {
                short8 bf = *(const short8*)(WA + (nt * 5 + kt) * 512 + lane * 8);
                acc[nt] = __builtin_amdgcn_mfma_f32_16x16x32_bf16(f.s, bf, acc[nt], 0, 0, 0);
            }
        }
        {   // kt=4: z_tex (q<2) | r_c (q==2) | one (q==3)
            Frag f;
            if (q < 2) {
                f.i[0] = pkbf2(ta.x, ta.y); f.i[1] = pkbf2(ta.z, ta.w);
                f.i[2] = pkbf2(tb.x, tb.y); f.i[3] = pkbf2(tb.z, tb.w);
            } else if (q == 2) {
                float2 e0 = __half22float2(*(__half2*)&got.x);   // charts 0,2
                float2 e1 = __half22float2(*(__half2*)&got.y);   // charts 4,6
                float2 e2 = __half22float2(*(__half2*)&got.z);   // charts 1,3
                float2 e3 = __half22float2(*(__half2*)&got.w);   // charts 5,7
                f.i[0] = pkbf2(e0.x, e2.x);
                f.i[1] = pkbf2(e0.y, e2.y);
                f.i[2] = pkbf2(e1.x, e3.x);
                f.i[3] = pkbf2(e1.y, e3.y);
            } else {
                f.i[0] = pkbf2(1.0f, 0.f); f.i[1] = 0; f.i[2] = 0; f.i[3] = 0;
            }
            #pragma unroll
            for (int nt = 0; nt < 4; nt++) {
                short8 bf = *(const short8*)(WA + (nt * 5 + 4) * 512 + lane * 8);
                acc[nt] = __builtin_amdgcn_mfma_f32_16x16x32_bf16(f.s, bf, acc[nt], 0, 0, 0);
            }
        }

        // prefetch z(tn+1): raw float4s, consumed one full stage later (R8 lesson)
        if (tn < 3) {
            const float4* pzn = (const float4*)(zrow + (tn + 1) * 256);
            const float4* ptn = (const float4*)(trow + (tn + 1) * 256);
            za = pzn[0]; zb = pzn[1]; ta = ptn[0]; tb = ptn[1];
        }

        // one-pass LayerNorm stats
        float mu[4], rsd[4];
        #pragma unroll
        for (int reg = 0; reg < 4; reg++) {
            float a = acc[0][reg], b = acc[1][reg], c = acc[2][reg], d = acc[3][reg];
            float s  = (a + b) + (c + d);
            float s2 = fmaf(a, a, fmaf(b, b, fmaf(c, c, d * d)));
            s  += __shfl_xor(s, 1);  s  += __shfl_xor(s, 2);
            s  += __shfl_xor(s, 4);  s  += __shfl_xor(s, 8);
            s2 += __shfl_xor(s2, 1); s2 += __shfl_xor(s2, 2);
            s2 += __shfl_xor(s2, 4); s2 += __shfl_xor(s2, 8);
            float m = s * (1.0f / 64.0f);
            mu[reg]  = m;
            rsd[reg] = rsqrtf(fmaf(s2, 1.0f / 64.0f, -m * m) + 1e-5f);
        }

        // g1 = gelu(LN(h)) -> scrA (bf16, swizzled groups)
        #pragma unroll
        for (int nt = 0; nt < 4; nt++) {
            int high = (nt & 1) * 2 + sub;
            #pragma unroll
            for (int reg = 0; reg < 4; reg++) {
                float hn = (acc[nt][reg] - mu[reg]) * rsd[reg] * lngv[nt] + lnbv[nt];
                int grp = gswz((q * 4 + reg) + 16 * high);
                scrA[(nt >> 1) * 512 + grp * 8 + j] = pkbf1(gelu_fast(hn));
            }
        }
    };

    // ---- pipeline prologue: ADVANCE(0) -> drain -> A2(0) ----
    short8 A2cur[2];
    ADVANCE(0);
    asm volatile("s_waitcnt lgkmcnt(0)" ::: "memory");
    {
        int grp = gswz(lane);
        A2cur[0] = *(const short8*)(scrA +       grp * 8);
        A2cur[1] = *(const short8*)(scrA + 512 + grp * 8);
    }

    for (int t = 0; t < 4; t++) {
        // ---- GEMM2(t) + b1 + gelu -> scrB ----
        #pragma unroll
        for (int nt = 0; nt < 4; nt++) {
            f32x4 a2 = {0.f, 0.f, 0.f, 0.f};
            a2 = __builtin_amdgcn_mfma_f32_16x16x32_bf16(A2cur[0], W1F[nt][0], a2, 0, 0, 0);
            a2 = __builtin_amdgcn_mfma_f32_16x16x32_bf16(A2cur[1], W1F[nt][1], a2, 0, 0, 0);
            int high = (nt & 1) * 2 + sub;
            #pragma unroll
            for (int reg = 0; reg < 4; reg++) {
                float h1v = gelu_fast(a2[reg] + b1v[nt]);
                int grp = gswz((q * 4 + reg) + 16 * high);
                scrB[(nt >> 1) * 512 + grp * 8 + j] = pkbf1(h1v);
            }
        }

        // ---- ADVANCE(t+1): its MFMA/LN work hides the g2-write latency ----
        if (t < 3) ADVANCE(t + 1);

        // ---- single drain per iteration ----
        asm volatile("s_waitcnt lgkmcnt(0)" ::: "memory");

        short8 A3[2];
        {
            int grp = gswz(lane);
            A3[0] = *(const short8*)(scrB +       grp * 8);
            A3[1] = *(const short8*)(scrB + 512 + grp * 8);
        }
        if (t < 3) {   // A2(t+1): read now, hidden under GEMM3(t)+store
            int grp = gswz(lane);
            A2cur[0] = *(const short8*)(scrA +       grp * 8);
            A2cur[1] = *(const short8*)(scrA + 512 + grp * 8);
        }

        // ---- GEMM3(t) + b2 (W2 fragments from LDS), coalesced store ----
        const long sOutBase = blockBase + wv * 64 + t * 16 + q * 4;
        #pragma unroll
        for (int nt = 0; nt < 2; nt++) {
            f32x4 a3 = {0.f, 0.f, 0.f, 0.f};
            short8 wA = W2L[(nt * 2 + 0) * 64 + lane];
            short8 wB = W2L[(nt * 2 + 1) * 64 + lane];
            a3 = __builtin_amdgcn_mfma_f32_16x16x32_bf16(A3[0], wA, a3, 0, 0, 0);
            a3 = __builtin_amdgcn_mfma_f32_16x16x32_bf16(A3[1], wB, a3, 0, 0, 0);
            #pragma unroll
            for (int reg = 0; reg < 4; reg++)
                out[(sOutBase + reg) * 32 + nt * 16 + col] = a3[reg] + b2v[nt];
        }
    }
}

extern "C" void kernel_launch(void* const* d_in, const int* in_sizes, int n_in,
                              void* d_out, int out_size, void* d_ws, size_t ws_size,
                              hipStream_t stream) {
    const int B = in_sizes[0] / 16;
    const int prepacked = (d_ws != nullptr && ws_size >= 32896) ? 1 : 0;
    if (prepacked) {
        hipLaunchKernelGGL(pack_weights, dim3(43), dim3(256), 0, stream,
            (const float*)d_in[2],  (const float*)d_in[3],
            (const float*)d_in[7],  (const float*)d_in[8],
            (const float*)d_in[11], (const float*)d_in[13],
            (const float*)d_in[6],  (const float*)d_in[5],
            (short*)d_ws);
    }
    dim3 grid(B / 256), block(256);
    hipLaunchKernelGGL(topo_mfma, grid, block, 0, stream,
        (const float*)d_in[0],  (const float*)d_in[1],
        (const float*)d_in[2],  (const float*)d_in[3],
        (const float*)d_in[4],  (const float*)d_in[5],
        (const float*)d_in[6],  (const float*)d_in[7],
        (const float*)d_in[8],  (const float*)d_in[9],
        (const float*)d_in[10], (const float*)d_in[11],
        (const float*)d_in[12], (const float*)d_in[13],
        (const float*)d_in[14],
        (const short*)d_ws, prepacked,
        (float*)d_out, B);
}

// Round 11
// 138.259 us; speedup vs baseline: 1.0400x; 1.0400x over previous
//
#include <hip/hip_runtime.h>
#include <hip/hip_bf16.h>
#include <hip/hip_fp16.h>

// TopologicalDecoder via MFMA. B=262144, L=16, H=64, C=8, O=32. f32 in/out.
// R11 = exact restoration of the R5 champion (44.0us dispatch, hbm_bytes
// ~64MB = ideal, bench 139.5us). Session evidence: the (256,4) 128-VGPR cap
// is binding; R6 (occupancy-5), R7/R9/R10 (lifetime-extending schedules) all
// spilled; R8 (lifetime-shortening) exposed latency. R5 is the measured
// optimum of this decomposition.
//
// GEMM1: U[b,160] @ Waug[160,64], U = [r(x)z (128) | z_tex (16) | r_c (8) | 1 | pad],
// biases folded, kt-outer. GEMM2: bf16(gelu(LN(h))) @ w1^T. GEMM3: bf16(gelu(.+b1)) @ w2^T.
// MFMA 16x16x32 bf16. A: m=lane&15,k=q*8+j; B: n=lane&15,same k;
// C/D: col=lane&15,row=q*4+reg (verified).

typedef __attribute__((ext_vector_type(8))) short short8;
typedef __attribute__((ext_vector_type(4))) float f32x4;

__device__ __forceinline__ int pkbf2(float a, float b) {
    union { __hip_bfloat162 h2; int i; } u;
    u.h2 = __float22bfloat162_rn(make_float2(a, b));   // v_cvt_pk_bf16_f32
    return u.i;
}
__device__ __forceinline__ short pkbf1(float a) { return (short)pkbf2(a, 0.f); }

// fast GELU (tanh-form): max abs err ~4e-4
__device__ __forceinline__ float gelu_fast(float x) {
    float x2 = x * x;
    float t  = __expf(fmaf(x2, 0.07135481f, 1.5957691f) * x);
    float r  = __builtin_amdgcn_rcpf(t + 1.0f);
    return fmaf(-x, r, x);
}
// packed-fragment flat short index for B[k][n] matrices (KT = K/32 tiles)
__device__ __forceinline__ int bpack(int k, int n, int KT) {
    return (((n >> 4) * KT + (k >> 5)) * 64 + (n & 15) + (((k & 31) >> 3) << 4)) * 8 + (k & 7);
}
// scratch group swizzle: spreads scatter writes across banks
__device__ __forceinline__ int gswz(int g) {
    return g ^ (((g >> 4) & 3) << 1) ^ ((g >> 3) & 1);
}
// pack 8 consecutive f32 into a bf16 fragment row
__device__ __forceinline__ short8 packrow8(const float* base) {
    const float4* p = (const float4*)base;
    float4 a = p[0], b = p[1];
    union { short8 s; int i[4]; } f;
    f.i[0] = pkbf2(a.x, a.y); f.i[1] = pkbf2(a.z, a.w);
    f.i[2] = pkbf2(b.x, b.y); f.i[3] = pkbf2(b.z, b.w);
    return f.s;
}

// ws layout (shorts): [0,10240) WAug bpack | [10240,14336) W1 frags | [14336,16384) W2 frags
// (bytes) [32768,32896) cvals float4[8] = {csq, 1-csq, 0.1*rb, 0}
// Parallel pack: blocks 0..39 -> WAug (1 elem/thread), 40 -> W1, 41 -> W2, 42 -> cvals.
__global__ void pack_weights(const float* __restrict__ cw, const float* __restrict__ cb,
                             const float* __restrict__ txw, const float* __restrict__ txb,
                             const float* __restrict__ w1,  const float* __restrict__ w2,
                             const float* __restrict__ cen, const float* __restrict__ rb,
                             short* __restrict__ ws)
{
    const int tid = threadIdx.x;
    const int b = blockIdx.x;
    if (b < 40) {
        int idx = b * 256 + tid;               // [0,10240)
        int k = idx >> 6, n = idx & 63;
        float v;
        if (k < 128)       v = cw[(k >> 4) * 1024 + n * 16 + (k & 15)];
        else if (k < 144)  v = txw[n * 16 + (k - 128)];
        else if (k < 152)  v = cb[(k - 144) * 64 + n];
        else if (k == 152) v = txb[n];
        else               v = 0.f;
        ws[bpack(k, n, 5)] = pkbf1(v);
    } else if (b == 40) {
        for (int f = tid; f < 512; f += 256) {          // W1: (nt,kt,lane)
            int lane = f & 63, e = f >> 6;
            int nt = e >> 1, kt = e & 1;
            int col = lane & 15, qq = lane >> 4;
            *(short8*)(ws + 10240 + f * 8) =
                packrow8(w1 + (nt * 16 + col) * 64 + kt * 32 + qq * 8);
        }
    } else if (b == 41) {
        int f = tid;                                     // W2: 256 entries
        int lane = f & 63, e = f >> 6;
        int nt = e >> 1, kt = e & 1;
        int col = lane & 15, qq = lane >> 4;
        *(short8*)(ws + 14336 + f * 8) =
            packrow8(w2 + (nt * 16 + col) * 64 + kt * 32 + qq * 8);
    } else {
        if (tid < 8) {
            float csq = 0.f;
            for (int l = 0; l < 16; l++) { float cv = cen[tid * 16 + l]; csq = fmaf(cv, cv, csq); }
            ((float4*)((char*)ws + 32768))[tid] =
                make_float4(csq, 1.0f - csq, 0.1f * rb[tid], 0.f);
        }
    }
}

// LDS layout (bytes): WAug 20480 | scratch 4x2048 | RS f16 [256][8] 4096 | W2L 4096 = 36864
constexpr int SCR_OFF = 20480;
constexpr int RS_OFF  = 28672;
constexpr int W2L_OFF = 32768;
constexpr int SMEM_SZ = 36864;

__global__ __launch_bounds__(256, 4) void topo_mfma(
    const float* __restrict__ zg,  const float* __restrict__ ztx,
    const float* __restrict__ cw,  const float* __restrict__ cb,
    const float* __restrict__ rw,  const float* __restrict__ rb,
    const float* __restrict__ cen, const float* __restrict__ txw,
    const float* __restrict__ txb, const float* __restrict__ lng,
    const float* __restrict__ lnb, const float* __restrict__ w1,
    const float* __restrict__ b1,  const float* __restrict__ w2,
    const float* __restrict__ b2,  const short* __restrict__ wsp,
    const int prepacked,
    float* __restrict__ out, int Btot)
{
    __shared__ __align__(16) char smem[SMEM_SZ];
    short* WA = (short*)smem;
    __half* RSh = (__half*)(smem + RS_OFF);
    const short8* W2L = (const short8*)(smem + W2L_OFF);

    const int tid = threadIdx.x;
    const int wv = tid >> 6, lane = tid & 63;
    const int q = lane >> 4, col = lane & 15;
    const int sub = (lane >> 3) & 1, j = lane & 7;

    // ---- stage WAug + W2 fragments into LDS ----
    if (prepacked) {
        const int4* src = (const int4*)wsp;
        int4* dst = (int4*)smem;
        #pragma unroll
        for (int i = 0; i < 5; i++) dst[i * 256 + tid] = src[i * 256 + tid];
        ((int4*)(smem + W2L_OFF))[tid] = ((const int4*)((const char*)wsp + 28672))[tid];
    } else {
        for (int idx = tid; idx < 160 * 64; idx += 256) {
            int k = idx >> 6, n = idx & 63;
            float v;
            if (k < 128)       v = cw[(k >> 4) * 1024 + n * 16 + (k & 15)];
            else if (k < 144)  v = txw[n * 16 + (k - 128)];
            else if (k < 152)  v = cb[(k - 144) * 64 + n];
            else if (k == 152) v = txb[n];
            else               v = 0.f;
            WA[bpack(k, n, 5)] = pkbf1(v);
        }
        {   // W2 frags -> LDS (256 entries, one per thread)
            int e = tid >> 6, ln = tid & 63;
            int nt = e >> 1, kt = e & 1;
            *(short8*)(smem + W2L_OFF + (e * 64 + ln) * 16) =
                packrow8(w2 + (nt * 16 + (ln & 15)) * 64 + kt * 32 + (ln >> 4) * 8);
        }
    }

    // ---- router (f32, own sample; branchless fast acosh, cvals-prepacked) ----
    const long sG = (long)blockIdx.x * 256 + tid;
    {
        float z[16];
        const float4* pg = (const float4*)(zg + sG * 16);
        #pragma unroll
        for (int v = 0; v < 4; v++) {
            float4 a = pg[v];
            z[v*4+0]=a.x; z[v*4+1]=a.y; z[v*4+2]=a.z; z[v*4+3]=a.w;
        }
        float r2 = 0.f;
        #pragma unroll
        for (int l = 0; l < 16; l++) r2 = fmaf(z[l], z[l], r2);
        const float inv_tau = __builtin_amdgcn_rcpf(fmaxf(2.0f * fmaxf(1.0f - r2, 0.001f), 0.01f));
        const float omr2 = 1.0f - r2;
        const float4* cvp = (const float4*)((const char*)wsp + 32768);
        float scv[8]; float smax = -1e30f;
        #pragma unroll
        for (int c = 0; c < 8; c++) {
            float csq, omc2, rb1;
            if (prepacked) {
                float4 kv = cvp[c]; csq = kv.x; omc2 = kv.y; rb1 = kv.z;
            } else {
                csq = 0.f;
                #pragma unroll
                for (int l = 0; l < 16; l++) { float cv = cen[c*16+l]; csq = fmaf(cv, cv, csq); }
                omc2 = 1.0f - csq; rb1 = 0.1f * rb[c];
            }
            const float4* cp = (const float4*)(cen + c * 16);
            const float4* rp = (const float4*)(rw  + c * 16);
            float zc = 0.f, dotv = 0.f;
            #pragma unroll
            for (int v = 0; v < 4; v++) {
                float4 cv = cp[v], rv = rp[v];
                zc   = fmaf(z[v*4+0],cv.x, fmaf(z[v*4+1],cv.y,
                       fmaf(z[v*4+2],cv.z, fmaf(z[v*4+3],cv.w, zc))));
                dotv = fmaf(z[v*4+0],rv.x, fmaf(z[v*4+1],rv.y,
                       fmaf(z[v*4+2],rv.z, fmaf(z[v*4+3],rv.w, dotv))));
            }
            float dsq = fmaf(-2.0f, zc, r2 + csq);
            float u = 2.0f * dsq * __builtin_amdgcn_rcpf(omr2 * omc2 + 0.001f);
            u = fmaxf(u, 0.001f);
            float dist  = __logf((1.0f + u) + __builtin_amdgcn_sqrtf(u * (u + 2.0f)));
            float score = (fmaf(0.1f, dotv, rb1) - dist) * inv_tau;
            scv[c] = score; smax = fmaxf(smax, score);
        }
        float esum = 0.f;
        #pragma unroll
        for (int c = 0; c < 8; c++) { scv[c] = __expf(scv[c] - smax); esum += scv[c]; }
        const float rinv = __builtin_amdgcn_rcpf(esum);
        union { ushort us[8]; int4 v; } hv;
        #pragma unroll
        for (int c = 0; c < 8; c++) {
            scv[c] *= rinv;
            // halves [0..3]=charts 0,2,4,6 ; [4..7]=charts 1,3,5,7
            hv.us[(c & 1) * 4 + (c >> 1)] = __half_as_ushort(__float2half_rn(scv[c]));
        }
        *(int4*)(RSh + tid * 8) = hv.v;
        float4* pr = (float4*)(out + (long)Btot * 32 + sG * 8);
        pr[0] = make_float4(scv[0], scv[1], scv[2], scv[3]);
        pr[1] = make_float4(scv[4], scv[5], scv[6], scv[7]);
    }

    // ---- per-wave register B-fragments for w1^T (from prepacked ws / global) ----
    short8 W1F[4][2];
    if (prepacked) {
        const short8* p1 = (const short8*)(wsp + 10240);
        #pragma unroll
        for (int nt = 0; nt < 4; nt++)
            #pragma unroll
            for (int kt = 0; kt < 2; kt++)
                W1F[nt][kt] = p1[(nt * 2 + kt) * 64 + lane];
    } else {
        const int kb = q * 8;
        #pragma unroll
        for (int nt = 0; nt < 4; nt++)
            #pragma unroll
            for (int kt = 0; kt < 2; kt++)
                W1F[nt][kt] = packrow8(w1 + (nt * 16 + col) * 64 + kt * 32 + kb);
    }
    // ---- per-lane epilogue constants (col-indexed, 14 regs) ----
    float lngv[4], lnbv[4], b1v[4], b2v[2];
    #pragma unroll
    for (int nt = 0; nt < 4; nt++) {
        lngv[nt] = lng[nt * 16 + col];
        lnbv[nt] = lnb[nt * 16 + col];
        b1v[nt]  = b1[nt * 16 + col];
    }
    b2v[0] = b2[col]; b2v[1] = b2[16 + col];

    __syncthreads();

    short* scr = (short*)(smem + SCR_OFF) + wv * 1024;
    union Frag { short8 s; int i[4]; };

    const long blockBase = (long)blockIdx.x * 256;
    const float* zrow = zg  + (blockBase + wv * 64 + col) * 16 + ((q & 1) << 3);
    const float* trow = ztx + (blockBase + wv * 64 + col) * 16 + ((q & 1) << 3);

    float4 za = ((const float4*)zrow)[0], zb = ((const float4*)zrow)[1];
    float4 ta = ((const float4*)trow)[0], tb = ((const float4*)trow)[1];

    for (int t = 0; t < 4; t++) {
        const int  mBase = wv * 64 + t * 16;
        const int  sL = mBase + col;                       // local sample (A-row m=col)
        const int  rsb = sL * 8;

        // rc[kt] = router weight of sample sL for chart 2kt+(q>>1), from f16 RS
        float rc[4];
        {
            union { unsigned long long u; __half2 h[2]; } rr;
            rr.u = *(const unsigned long long*)(RSh + rsb + ((q >> 1) << 2));
            float2 f0 = __half22float2(rr.h[0]);
            float2 f1 = __half22float2(rr.h[1]);
            rc[0] = f0.x; rc[1] = f0.y; rc[2] = f1.x; rc[3] = f1.y;
        }

        // ---- GEMM1 (kt-outer: one U-fragment live at a time; biases folded) ----
        f32x4 acc[4] = {{0.f,0.f,0.f,0.f},{0.f,0.f,0.f,0.f},{0.f,0.f,0.f,0.f},{0.f,0.f,0.f,0.f}};
        __builtin_amdgcn_s_setprio(1);
        #pragma unroll
        for (int kt = 0; kt < 4; kt++) {
            float r = rc[kt];
            Frag f;
            f.i[0] = pkbf2(r * za.x, r * za.y);
            f.i[1] = pkbf2(r * za.z, r * za.w);
            f.i[2] = pkbf2(r * zb.x, r * zb.y);
            f.i[3] = pkbf2(r * zb.z, r * zb.w);
            #pragma unroll
            for (int nt = 0; nt < 4; nt++) {
                short8 bf = *(const short8*)(WA + (nt * 5 + kt) * 512 + lane * 8);
                acc[nt] = __builtin_amdgcn_mfma_f32_16x16x32_bf16(f.s, bf, acc[nt], 0, 0, 0);
            }
        }
        {   // kt=4: z_tex (q<2) | r_c (q==2) | one (q==3)
            Frag f;
            if (q < 2) {
                f.i[0] = pkbf2(ta.x, ta.y); f.i[1] = pkbf2(ta.z, ta.w);
                f.i[2] = pkbf2(tb.x, tb.y); f.i[3] = pkbf2(tb.z, tb.w);
            } else if (q == 2) {
                union { int4 u; __half2 h[4]; } rv;
                rv.u = *(const int4*)(RSh + rsb);
                float2 e0 = __half22float2(rv.h[0]);   // charts 0,2
                float2 e1 = __half22float2(rv.h[1]);   // charts 4,6
                float2 e2 = __half22float2(rv.h[2]);   // charts 1,3
                float2 e3 = __half22float2(rv.h[3]);   // charts 5,7
                f.i[0] = pkbf2(e0.x, e2.x);            // 0,1
                f.i[1] = pkbf2(e0.y, e2.y);            // 2,3
                f.i[2] = pkbf2(e1.x, e3.x);            // 4,5
                f.i[3] = pkbf2(e1.y, e3.y);            // 6,7
            } else {
                f.i[0] = pkbf2(1.0f, 0.f); f.i[1] = 0; f.i[2] = 0; f.i[3] = 0;
            }
            #pragma unroll
            for (int nt = 0; nt < 4; nt++) {
                short8 bf = *(const short8*)(WA + (nt * 5 + 4) * 512 + lane * 8);
                acc[nt] = __builtin_amdgcn_mfma_f32_16x16x32_bf16(f.s, bf, acc[nt], 0, 0, 0);
            }
        }
        __builtin_amdgcn_s_setprio(0);

        // ---- prefetch next tile's z/ztx (hidden under LN/GEMM2/GEMM3) ----
        if (t < 3) {
            const float4* pzn = (const float4*)(zrow + (t + 1) * 256);
            const float4* ptn = (const float4*)(trow + (t + 1) * 256);
            za = pzn[0]; zb = pzn[1]; ta = ptn[0]; tb = ptn[1];
        }

        // ---- one-pass LayerNorm stats across 64 cols (16 lanes x 4 nt) per row ----
        float mu[4], rsd[4];
        #pragma unroll
        for (int reg = 0; reg < 4; reg++) {
            float a = acc[0][reg], b = acc[1][reg], c = acc[2][reg], d = acc[3][reg];
            float s  = (a + b) + (c + d);
            float s2 = fmaf(a, a, fmaf(b, b, fmaf(c, c, d * d)));
            s  += __shfl_xor(s, 1);  s  += __shfl_xor(s, 2);
            s  += __shfl_xor(s, 4);  s  += __shfl_xor(s, 8);
            s2 += __shfl_xor(s2, 1); s2 += __shfl_xor(s2, 2);
            s2 += __shfl_xor(s2, 4); s2 += __shfl_xor(s2, 8);
            float m = s * (1.0f / 64.0f);
            mu[reg]  = m;
            rsd[reg] = rsqrtf(fmaf(s2, 1.0f / 64.0f, -m * m) + 1e-5f);
        }

        // ---- g1 = gelu(LN(h)) -> scratch (bf16, swizzled groups) ----
        #pragma unroll
        for (int nt = 0; nt < 4; nt++) {
            int high = (nt & 1) * 2 + sub;
            #pragma unroll
            for (int reg = 0; reg < 4; reg++) {
                float hn = (acc[nt][reg] - mu[reg]) * rsd[reg] * lngv[nt] + lnbv[nt];
                int grp = gswz((q * 4 + reg) + 16 * high);
                scr[(nt >> 1) * 512 + grp * 8 + j] = pkbf1(gelu_fast(hn));
            }
        }
        asm volatile("s_waitcnt lgkmcnt(0)" ::: "memory");

        short8 A2[2];
        {
            int grp = gswz(lane);
            A2[0] = *(const short8*)(scr +       grp * 8);
            A2[1] = *(const short8*)(scr + 512 + grp * 8);
        }

        // ---- GEMM2 + b1 + gelu -> scratch ----
        #pragma unroll
        for (int nt = 0; nt < 4; nt++) {
            f32x4 a2 = {0.f, 0.f, 0.f, 0.f};
            __builtin_amdgcn_s_setprio(1);
            a2 = __builtin_amdgcn_mfma_f32_16x16x32_bf16(A2[0], W1F[nt][0], a2, 0, 0, 0);
            a2 = __builtin_amdgcn_mfma_f32_16x16x32_bf16(A2[1], W1F[nt][1], a2, 0, 0, 0);
            __builtin_amdgcn_s_setprio(0);
            int high = (nt & 1) * 2 + sub;
            #pragma unroll
            for (int reg = 0; reg < 4; reg++) {
                float h1v = gelu_fast(a2[reg] + b1v[nt]);
                int grp = gswz((q * 4 + reg) + 16 * high);
                scr[(nt >> 1) * 512 + grp * 8 + j] = pkbf1(h1v);
            }
        }
        asm volatile("s_waitcnt lgkmcnt(0)" ::: "memory");

        short8 A3[2];
        {
            int grp = gswz(lane);
            A3[0] = *(const short8*)(scr +       grp * 8);
            A3[1] = *(const short8*)(scr + 512 + grp * 8);
        }

        // ---- GEMM3 + b2 (W2 fragments from LDS), store ----
        const long sOutBase = blockBase + mBase + q * 4;
        #pragma unroll
        for (int nt = 0; nt < 2; nt++) {
            f32x4 a3 = {0.f, 0.f, 0.f, 0.f};
            short8 wA = W2L[(nt * 2 + 0) * 64 + lane];
            short8 wB = W2L[(nt * 2 + 1) * 64 + lane];
            __builtin_amdgcn_s_setprio(1);
            a3 = __builtin_amdgcn_mfma_f32_16x16x32_bf16(A3[0], wA, a3, 0, 0, 0);
            a3 = __builtin_amdgcn_mfma_f32_16x16x32_bf16(A3[1], wB, a3, 0, 0, 0);
            __builtin_amdgcn_s_setprio(0);
            #pragma unroll
            for (int reg = 0; reg < 4; reg++)
                out[(sOutBase + reg) * 32 + nt * 16 + col] = a3[reg] + b2v[nt];
        }
    }
}

extern "C" void kernel_launch(void* const* d_in, const int* in_sizes, int n_in,
                              void* d_out, int out_size, void* d_ws, size_t ws_size,
                              hipStream_t stream) {
    const int B = in_sizes[0] / 16;
    const int prepacked = (d_ws != nullptr && ws_size >= 32896) ? 1 : 0;
    if (prepacked) {
        hipLaunchKernelGGL(pack_weights, dim3(43), dim3(256), 0, stream,
            (const float*)d_in[2],  (const float*)d_in[3],
            (const float*)d_in[7],  (const float*)d_in[8],
            (const float*)d_in[11], (const float*)d_in[13],
            (const float*)d_in[6],  (const float*)d_in[5],
            (short*)d_ws);
    }
    dim3 grid(B / 256), block(256);
    hipLaunchKernelGGL(topo_mfma, grid, block, 0, stream,
        (const float*)d_in[0],  (const float*)d_in[1],
        (const float*)d_in[2],  (const float*)d_in[3],
        (const float*)d_in[4],  (const float*)d_in[5],
        (const float*)d_in[6],  (const float*)d_in[7],
        (const float*)d_in[8],  (const float*)d_in[9],
        (const float*)d_in[10], (const float*)d_in[11],
        (const float*)d_in[12], (const float*)d_in[13],
        (const float*)d_in[14],
        (const short*)d_ws, prepacked,
        (float*)d_out, B);
}